// Round 5
// baseline (773.688 us; speedup 1.0000x reference)
//
#include <hip/hip_runtime.h>
#include <stdint.h>

#define D_IN 1024
#define C1   1024   // H1*HID
#define C2   256    // H2*HID
#define NEG  0.2f

typedef unsigned int u32;
typedef uint16_t u16;
typedef __attribute__((ext_vector_type(8))) short bf16x8;
typedef __attribute__((ext_vector_type(4))) float f32x4;

__device__ __forceinline__ float bf2f(u32 lo16) { return __uint_as_float(lo16 << 16); }
__device__ __forceinline__ u16 f2bf(float f) {
  u32 u = __float_as_uint(f);
  u += 0x7fffu + ((u >> 16) & 1u);   // RNE
  return (u16)(u >> 16);
}

__device__ __forceinline__ void gload16(const u16* g, u16* l) {
  __builtin_amdgcn_global_load_lds(
      (const __attribute__((address_space(1))) unsigned int*)g,
      (__attribute__((address_space(3))) unsigned int*)l,
      16, 0, 0);
}

// ---------------- cast x (f32) -> padded bf16 A [Mp][1024], zero pad rows ----
__global__ void cast_x_k(const float* __restrict__ x, u16* __restrict__ A,
                         int nrows, int Mp) {
  long long idx = (long long)blockIdx.x * blockDim.x + threadIdx.x;
  long long total = (long long)Mp * (D_IN / 8);
  if (idx >= total) return;
  long long base = idx * 8;
  int row = (int)(base >> 10);  // D_IN==1024
  u32 o0 = 0, o1 = 0, o2 = 0, o3 = 0;
  if (row < nrows) {
    const float4* px = (const float4*)(x + base);
    float4 v0 = px[0], v1 = px[1];
    o0 = (u32)f2bf(v0.x) | ((u32)f2bf(v0.y) << 16);
    o1 = (u32)f2bf(v0.z) | ((u32)f2bf(v0.w) << 16);
    o2 = (u32)f2bf(v1.x) | ((u32)f2bf(v1.y) << 16);
    o3 = (u32)f2bf(v1.z) | ((u32)f2bf(v1.w) << 16);
  }
  *(uint4*)(A + base) = make_uint4(o0, o1, o2, o3);
}

// ---------------- transpose+cast W [K][Nc] f32 -> Wt [Nc][K] bf16 ------------
__global__ void transpose_cast_k(const float* __restrict__ W, u16* __restrict__ Wt,
                                 int K, int Nc) {
  __shared__ float sh[32][33];
  int k0 = blockIdx.x * 32, n0 = blockIdx.y * 32;
  int tx = threadIdx.x, ty = threadIdx.y;  // block (32,8)
#pragma unroll
  for (int i = 0; i < 32; i += 8)
    sh[ty + i][tx] = W[(long long)(k0 + ty + i) * Nc + (n0 + tx)];
  __syncthreads();
#pragma unroll
  for (int i = 0; i < 32; i += 8)
    Wt[(long long)(n0 + ty + i) * K + (k0 + tx)] = f2bf(sh[tx][ty + i]);
}

// ---------------- concat two bias vectors -----------------------------------
__global__ void concat_bias_k(const float* __restrict__ a, const float* __restrict__ b,
                              float* __restrict__ o, int na, int nb) {
  int i = blockIdx.x * 256 + threadIdx.x;
  if (i < na) o[i] = a[i];
  else if (i < na + nb) o[i] = b[i - na];
}

// ============ 256x256 BK=64 8-wave phase-interleaved MFMA GEMM ===============
// C[M][TN] = A[M][K] * Bt[TN][K]^T + bias.  512 thr = 8 waves (2M x 4N),
// per-wave 128x64 output (acc[8][4] 16x16 frags).  LDS 128 KiB:
// [dbuf2][half2][128x64] for A and B.  4 quadrant phases per K-tile, each
// {stage prefetch | ds_read subtile -> s_barrier -> setprio1 -> 16 MFMA ->
// setprio0 -> barrier}.  Deep stage stream (>=3-phase lead for every half):
//   ph1: B0,B1(t+1)   [4-phase lead]
//   ph2: A1(t+1)      [3-phase lead]
//   ph4: A0(t+2)      [5-phase lead]
// Counted s_waitcnt vmcnt(2) once per K-tile (allows A0(t+2) in flight);
// drain vmcnt(0) only at the tail.  Race-free: a buffer's B regions are dead
// after ph2 of their tile, A regions after ph3; every stage lands >=1 barrier
// after the last read of its destination region.
template <int TN>
__global__ __launch_bounds__(512, 2) void gemm8_k(
    const u16* __restrict__ A, const u16* __restrict__ Bt,
    const float* __restrict__ bias, u16* __restrict__ C, int K) {
  __shared__ u16 As[2][2][8192];
  __shared__ u16 Bs[2][2][8192];
  const int nx = gridDim.x, ny = gridDim.y;
  const int nwg = nx * ny;
  int id = blockIdx.y * nx + blockIdx.x;
  int q = nwg >> 3, r = nwg & 7;
  int xcd = id & 7, loc = id >> 3;
  int sid = (xcd < r ? xcd * (q + 1) : r * (q + 1) + (xcd - r) * q) + loc;
  const int m0 = (sid / ny) * 256;   // n varies fastest within an XCD
  const int n0 = (sid % ny) * 256;

  const int tid = threadIdx.x;
  const int lane = tid & 63;
  const int wave = tid >> 6;
  const int wm = wave >> 2;          // 0..1  (A half)
  const int wn = wave & 3;           // 0..3
  const int bh = wn >> 1;            // B half this wave reads
  const int bql = (wn & 1) * 2048;   // B quarter offset within half (u16)

  const int srow = tid >> 2;         // staging row 0..127
  const int kq   = tid & 3;          // physical k-chunk
  const int ksw  = (kq ^ ((srow >> 1) & 3)) * 8;  // swizzled src col (u16)

  const int nt = K / 64;

  const u16* gA[2] = { A + (long long)(m0 + srow) * K + ksw,
                       A + (long long)(m0 + 128 + srow) * K + ksw };
  const u16* gB[2] = { Bt + (long long)(n0 + srow) * K + ksw,
                       Bt + (long long)(n0 + 128 + srow) * K + ksw };

  auto stageA = [&](int kt, int h) {
    int db = kt & 1;
    gload16(gA[h] + kt * 64,      &As[db][h][tid * 8]);
    gload16(gA[h] + kt * 64 + 32, &As[db][h][4096 + tid * 8]);
  };
  auto stageB = [&](int kt, int h) {
    int db = kt & 1;
    gload16(gB[h] + kt * 64,      &Bs[db][h][tid * 8]);
    gload16(gB[h] + kt * 64 + 32, &Bs[db][h][4096 + tid * 8]);
  };

  // fragment read base: frow*32 + physchunk*8 (u16), physchunk = lq ^ s(frow)
  const int rbase = (lane & 15) * 32 + (((lane >> 4) ^ ((lane >> 1) & 3)) << 3);

  f32x4 acc[8][4] = {};
  bf16x8 av[4][2], bv[4][2];

  // ---- prologue: tile0 fully + A0(tile1); counted wait ----
  stageA(0, 0); stageA(0, 1); stageB(0, 0); stageB(0, 1);
  if (nt > 1) {
    stageA(1, 0);
    asm volatile("s_waitcnt vmcnt(2)" ::: "memory");
  } else {
    asm volatile("s_waitcnt vmcnt(0)" ::: "memory");
  }
  __builtin_amdgcn_s_barrier();

  for (int t = 0; t < nt; ++t) {
    const int cur = t & 1;
    const u16* Al = &As[cur][wm][0];
    const u16* Bl = &Bs[cur][bh][0];

    // ---- phase 1: Q1 (m-frags 0..3, n-frags 0..1); stage B0,B1(t+1) ----
    if (t + 1 < nt) { stageB(t + 1, 0); stageB(t + 1, 1); }
#pragma unroll
    for (int i = 0; i < 4; ++i) {
      av[i][0] = *(const bf16x8*)(Al + i * 512 + rbase);
      av[i][1] = *(const bf16x8*)(Al + 4096 + i * 512 + rbase);
    }
#pragma unroll
    for (int j = 0; j < 2; ++j) {
      bv[j][0] = *(const bf16x8*)(Bl + bql + j * 512 + rbase);
      bv[j][1] = *(const bf16x8*)(Bl + 4096 + bql + j * 512 + rbase);
    }
    __builtin_amdgcn_s_barrier();
    __builtin_amdgcn_s_setprio(1);
#pragma unroll
    for (int i = 0; i < 4; ++i)
#pragma unroll
      for (int j = 0; j < 2; ++j) {
        acc[i][j] = __builtin_amdgcn_mfma_f32_16x16x32_bf16(av[i][0], bv[j][0], acc[i][j], 0, 0, 0);
        acc[i][j] = __builtin_amdgcn_mfma_f32_16x16x32_bf16(av[i][1], bv[j][1], acc[i][j], 0, 0, 0);
      }
    __builtin_amdgcn_s_setprio(0);
    __builtin_amdgcn_s_barrier();

    // ---- phase 2: Q2 (m-frags 0..3, n-frags 2..3); stage A1(t+1) ----
    if (t + 1 < nt) stageA(t + 1, 1);
#pragma unroll
    for (int j = 2; j < 4; ++j) {
      bv[j][0] = *(const bf16x8*)(Bl + bql + j * 512 + rbase);
      bv[j][1] = *(const bf16x8*)(Bl + 4096 + bql + j * 512 + rbase);
    }
    __builtin_amdgcn_s_barrier();
    __builtin_amdgcn_s_setprio(1);
#pragma unroll
    for (int i = 0; i < 4; ++i)
#pragma unroll
      for (int j = 2; j < 4; ++j) {
        acc[i][j] = __builtin_amdgcn_mfma_f32_16x16x32_bf16(av[i][0], bv[j][0], acc[i][j], 0, 0, 0);
        acc[i][j] = __builtin_amdgcn_mfma_f32_16x16x32_bf16(av[i][1], bv[j][1], acc[i][j], 0, 0, 0);
      }
    __builtin_amdgcn_s_setprio(0);
    __builtin_amdgcn_s_barrier();

    // ---- phase 3: Q3 (m-frags 4..7, n-frags 2..3); no stage ----
#pragma unroll
    for (int i = 0; i < 4; ++i) {
      av[i][0] = *(const bf16x8*)(Al + (4 + i) * 512 + rbase);
      av[i][1] = *(const bf16x8*)(Al + 4096 + (4 + i) * 512 + rbase);
    }
    __builtin_amdgcn_s_barrier();
    __builtin_amdgcn_s_setprio(1);
#pragma unroll
    for (int i = 0; i < 4; ++i)
#pragma unroll
      for (int j = 2; j < 4; ++j) {
        acc[4 + i][j] = __builtin_amdgcn_mfma_f32_16x16x32_bf16(av[i][0], bv[j][0], acc[4 + i][j], 0, 0, 0);
        acc[4 + i][j] = __builtin_amdgcn_mfma_f32_16x16x32_bf16(av[i][1], bv[j][1], acc[4 + i][j], 0, 0, 0);
      }
    __builtin_amdgcn_s_setprio(0);
    __builtin_amdgcn_s_barrier();

    // ---- phase 4: Q4 (m-frags 4..7, n-frags 0..1); stage A0(t+2) ----
    if (t + 2 < nt) stageA(t + 2, 0);
    __builtin_amdgcn_s_barrier();
    __builtin_amdgcn_s_setprio(1);
#pragma unroll
    for (int i = 0; i < 4; ++i)
#pragma unroll
      for (int j = 0; j < 2; ++j) {
        acc[4 + i][j] = __builtin_amdgcn_mfma_f32_16x16x32_bf16(av[i][0], bv[j][0], acc[4 + i][j], 0, 0, 0);
        acc[4 + i][j] = __builtin_amdgcn_mfma_f32_16x16x32_bf16(av[i][1], bv[j][1], acc[4 + i][j], 0, 0, 0);
      }
    __builtin_amdgcn_s_setprio(0);
    if (t + 2 < nt) {
      asm volatile("s_waitcnt vmcnt(2)" ::: "memory");
    } else if (t + 1 < nt) {
      asm volatile("s_waitcnt vmcnt(0)" ::: "memory");
    }
    __builtin_amdgcn_s_barrier();
  }

  // ---- epilogue: D mapping col=lane&15, row=(lane>>4)*4+j ----
#pragma unroll
  for (int mf = 0; mf < 8; ++mf) {
    int r0 = m0 + wm * 128 + mf * 16 + ((lane >> 4) << 2);
#pragma unroll
    for (int nf = 0; nf < 4; ++nf) {
      int c = n0 + wn * 64 + nf * 16 + (lane & 15);
      float b = bias[c];
#pragma unroll
      for (int j = 0; j < 4; ++j)
        C[(long long)(r0 + j) * TN + c] = f2bf(acc[mf][nf][j] + b);
    }
  }
}

// ---------------- CSR build (by dst) ----------------------------------------
__global__ void count_k(const int* __restrict__ ei, int* __restrict__ counts,
                        int E0, int E) {
  for (int e = blockIdx.x * blockDim.x + threadIdx.x; e < E;
       e += gridDim.x * blockDim.x) {
    int dst = (e < E0) ? ei[E0 + e] : e - E0;
    atomicAdd(&counts[dst], 1);
  }
}

// hierarchical scan: blocksum -> scan partials (1 block) -> local scan + off
__global__ void blocksum_k(const int* __restrict__ counts, int* __restrict__ bsum, int n) {
  int i = blockIdx.x * 256 + threadIdx.x;
  int v = (i < n) ? counts[i] : 0;
#pragma unroll
  for (int off = 1; off < 64; off <<= 1) v += __shfl_xor(v, off);
  __shared__ int sh[4];
  if ((threadIdx.x & 63) == 0) sh[threadIdx.x >> 6] = v;
  __syncthreads();
  if (threadIdx.x == 0) bsum[blockIdx.x] = sh[0] + sh[1] + sh[2] + sh[3];
}

__global__ void scanb_k(const int* __restrict__ bsum, int* __restrict__ boff,
                        int nb, int* __restrict__ indptr, int n, int E) {
  __shared__ int sh[256];
  int i = threadIdx.x;
  int v = (i < nb) ? bsum[i] : 0;
  sh[i] = v;
  __syncthreads();
  int sum = v;
  for (int off = 1; off < 256; off <<= 1) {
    int t = (i >= off) ? sh[i - off] : 0;
    __syncthreads();
    sum += t;
    sh[i] = sum;
    __syncthreads();
  }
  if (i < nb) boff[i] = sum - v;  // exclusive
  if (i == 0) indptr[n] = E;
}

__global__ void scanf_k(const int* __restrict__ counts, const int* __restrict__ boff,
                        int* __restrict__ indptr, int n) {
  __shared__ int sh[256];
  int b = blockIdx.x;
  int i = b * 256 + threadIdx.x;
  int v = (i < n) ? counts[i] : 0;
  sh[threadIdx.x] = v;
  __syncthreads();
  int sum = v;
  for (int off = 1; off < 256; off <<= 1) {
    int t = (threadIdx.x >= off) ? sh[threadIdx.x - off] : 0;
    __syncthreads();
    sum += t;
    sh[threadIdx.x] = sum;
    __syncthreads();
  }
  if (i < n) indptr[i] = boff[b] + sum - v;
}

// store SRC id (not edge id) in CSR order
__global__ void scatter_k(const int* __restrict__ ei, const int* __restrict__ indptr,
                          int* __restrict__ cursor, int* __restrict__ esrc,
                          int E0, int E) {
  for (int e = blockIdx.x * blockDim.x + threadIdx.x; e < E;
       e += gridDim.x * blockDim.x) {
    int dst, src;
    if (e < E0) { src = ei[e]; dst = ei[E0 + e]; } else { src = dst = e - E0; }
    int pos = atomicAdd(&cursor[dst], 1);
    esrc[indptr[dst] + pos] = src;
  }
}

// ---------------- fused edge layer 1 (H=4): alpha+softmax+agg, online --------
__global__ __launch_bounds__(256) void fused_edge1_k(
    const u16* __restrict__ XLR, const int* __restrict__ indptr,
    const int* __restrict__ esrc, const float* __restrict__ att,
    const float* __restrict__ bias, u16* __restrict__ X2, int N) {
  int d = blockIdx.x;
  int tid = threadIdx.x;
  int c0 = tid * 4;  // channel in [0,1024); head = tid>>6
  if (d >= N) {
    *(ushort4*)(X2 + (long long)d * C1 + c0) = make_ushort4(0, 0, 0, 0);
    return;
  }
  ushort4 xr4 = *(const ushort4*)(XLR + (long long)d * 2048 + 1024 + c0);
  float xr0 = bf2f(xr4.x), xr1 = bf2f(xr4.y), xr2 = bf2f(xr4.z), xr3 = bf2f(xr4.w);
  float4 at = *(const float4*)(att + c0);

  float m = -INFINITY, l = 0.f;
  float a0 = 0.f, a1 = 0.f, a2 = 0.f, a3 = 0.f;
  int p = indptr[d], pend = indptr[d + 1];
  int src = esrc[p];
  ushort4 xl4 = *(const ushort4*)(XLR + (long long)src * 2048 + c0);
  while (p < pend) {
    ushort4 cur = xl4;
    int pn = p + 1;
    if (pn < pend) {
      int sn = esrc[pn];
      xl4 = *(const ushort4*)(XLR + (long long)sn * 2048 + c0);
    }
    float x0 = bf2f(cur.x), x1 = bf2f(cur.y), x2 = bf2f(cur.z), x3 = bf2f(cur.w);
    float m0 = x0 + xr0, m1 = x1 + xr1, m2 = x2 + xr2, m3 = x3 + xr3;
    float e0 = m0 > 0.f ? m0 : NEG * m0;
    float e1 = m1 > 0.f ? m1 : NEG * m1;
    float e2 = m2 > 0.f ? m2 : NEG * m2;
    float e3 = m3 > 0.f ? m3 : NEG * m3;
    float s = at.x * e0 + at.y * e1 + at.z * e2 + at.w * e3;
#pragma unroll
    for (int off = 1; off < 64; off <<= 1) s += __shfl_xor(s, off);
    float mnew = fmaxf(m, s);
    float scale = __expf(m - mnew);  // first iter: exp(-inf)=0
    float w = __expf(s - mnew);
    l = l * scale + w;
    a0 = a0 * scale + w * x0;
    a1 = a1 * scale + w * x1;
    a2 = a2 * scale + w * x2;
    a3 = a3 * scale + w * x3;
    m = mnew;
    p = pn;
  }
  float inv = 1.f / (l + 1e-16f);
  float4 b = *(const float4*)(bias + c0);
  ushort4 o;
  o.x = f2bf(fmaxf(a0 * inv + b.x, 0.f));
  o.y = f2bf(fmaxf(a1 * inv + b.y, 0.f));
  o.z = f2bf(fmaxf(a2 * inv + b.z, 0.f));
  o.w = f2bf(fmaxf(a3 * inv + b.w, 0.f));
  *(ushort4*)(X2 + (long long)d * C1 + c0) = o;
}

// ---------------- fused edge layer 2 (H=1): one wave per dst, f32 out --------
__global__ __launch_bounds__(256) void fused_edge2_k(
    const u16* __restrict__ XLR, const int* __restrict__ indptr,
    const int* __restrict__ esrc, const float* __restrict__ att,
    const float* __restrict__ bias, float* __restrict__ out, int N) {
  int d = blockIdx.x * 4 + (threadIdx.x >> 6);
  if (d >= N) return;
  int lane = threadIdx.x & 63;
  int c0 = lane * 4;
  ushort4 xr4 = *(const ushort4*)(XLR + (long long)d * 512 + 256 + c0);
  float xr0 = bf2f(xr4.x), xr1 = bf2f(xr4.y), xr2 = bf2f(xr4.z), xr3 = bf2f(xr4.w);
  float4 at = *(const float4*)(att + c0);

  float m = -INFINITY, l = 0.f;
  float a0 = 0.f, a1 = 0.f, a2 = 0.f, a3 = 0.f;
  int p = indptr[d], pend = indptr[d + 1];
  int src = esrc[p];
  ushort4 xl4 = *(const ushort4*)(XLR + (long long)src * 512 + c0);
  while (p < pend) {
    ushort4 cur = xl4;
    int pn = p + 1;
    if (pn < pend) {
      int sn = esrc[pn];
      xl4 = *(const ushort4*)(XLR + (long long)sn * 512 + c0);
    }
    float x0 = bf2f(cur.x), x1 = bf2f(cur.y), x2 = bf2f(cur.z), x3 = bf2f(cur.w);
    float m0 = x0 + xr0, m1 = x1 + xr1, m2 = x2 + xr2, m3 = x3 + xr3;
    float e0 = m0 > 0.f ? m0 : NEG * m0;
    float e1 = m1 > 0.f ? m1 : NEG * m1;
    float e2 = m2 > 0.f ? m2 : NEG * m2;
    float e3 = m3 > 0.f ? m3 : NEG * m3;
    float s = at.x * e0 + at.y * e1 + at.z * e2 + at.w * e3;
#pragma unroll
    for (int off = 1; off < 64; off <<= 1) s += __shfl_xor(s, off);
    float mnew = fmaxf(m, s);
    float scale = __expf(m - mnew);
    float w = __expf(s - mnew);
    l = l * scale + w;
    a0 = a0 * scale + w * x0;
    a1 = a1 * scale + w * x1;
    a2 = a2 * scale + w * x2;
    a3 = a3 * scale + w * x3;
    m = mnew;
    p = pn;
  }
  float inv = 1.f / (l + 1e-16f);
  float4 b = *(const float4*)(bias + c0);
  float4 o;
  o.x = fmaxf(a0 * inv + b.x, 0.f);
  o.y = fmaxf(a1 * inv + b.y, 0.f);
  o.z = fmaxf(a2 * inv + b.z, 0.f);
  o.w = fmaxf(a3 * inv + b.w, 0.f);
  *(float4*)(out + (long long)d * C2 + c0) = o;
}

// =============================================================================
extern "C" void kernel_launch(void* const* d_in, const int* in_sizes, int n_in,
                              void* d_out, int out_size, void* d_ws, size_t ws_size,
                              hipStream_t stream) {
  const float* x     = (const float*)d_in[0];
  const int*   ei    = (const int*)d_in[1];
  const float* W1l   = (const float*)d_in[2];
  const float* b1l   = (const float*)d_in[3];
  const float* W1r   = (const float*)d_in[4];
  const float* b1r   = (const float*)d_in[5];
  const float* att1  = (const float*)d_in[6];
  const float* bias1 = (const float*)d_in[7];
  const float* W2l   = (const float*)d_in[8];
  const float* b2l   = (const float*)d_in[9];
  const float* W2r   = (const float*)d_in[10];
  const float* b2r   = (const float*)d_in[11];
  const float* att2  = (const float*)d_in[12];
  const float* bias2 = (const float*)d_in[13];

  const int N  = in_sizes[0] / D_IN;  // 50000
  const int E0 = in_sizes[1] / 2;     // 400000
  const int E  = E0 + N;              // with self-loops
  const int Mp = (N + 255) & ~255;    // 50176 (multiple of 256)
  const int NB = (N + 255) / 256;     // scan blocks (196)

  char* p = (char*)d_ws;
  auto alloc = [&](size_t bytes) -> char* {
    char* r = p;
    p += (bytes + 255) & ~(size_t)255;
    return r;
  };
  u16* A_bf  = (u16*)alloc((size_t)Mp * D_IN * 2);   // x bf16; later X2 (layer-2 A)
  u16* XLR1  = (u16*)alloc((size_t)Mp * 2048 * 2);   // [xl|xr] layer 1; later XLR2
  u16* W1t   = (u16*)alloc((size_t)2048 * D_IN * 2);
  u16* W2t   = (u16*)alloc((size_t)512 * C1 * 2);
  float* bc1 = (float*)alloc(2048 * 4);
  float* bc2 = (float*)alloc(512 * 4);
  int* counts = (int*)alloc((size_t)N * 4);
  int* cursor = (int*)alloc((size_t)N * 4);
  int* indptr = (int*)alloc((size_t)(N + 1) * 4);
  int* esrc   = (int*)alloc((size_t)E * 4);
  int* bsum   = (int*)alloc((size_t)NB * 4);
  int* boff   = (int*)alloc((size_t)NB * 4);
  u16* X2   = A_bf;   // alias: A_bf dead after GEMM1
  u16* XLR2 = XLR1;   // alias: XLR1 dead after fused_edge1

  size_t need = (size_t)(p - (char*)d_ws);
  if (ws_size < need) {
    hipMemsetAsync(d_out, 0xFF, 4, stream);  // NaN sentinel
    return;
  }

  hipMemsetAsync(counts, 0, (size_t)N * 4, stream);
  hipMemsetAsync(cursor, 0, (size_t)N * 4, stream);

  // ---- casts / transposes / bias concat ----
  {
    long long tot = (long long)Mp * (D_IN / 8);
    cast_x_k<<<(int)((tot + 255) / 256), 256, 0, stream>>>(x, A_bf, N, Mp);
  }
  dim3 tb(32, 8);
  transpose_cast_k<<<dim3(D_IN / 32, C1 / 32), tb, 0, stream>>>(W1l, W1t, D_IN, C1);
  transpose_cast_k<<<dim3(D_IN / 32, C1 / 32), tb, 0, stream>>>(W1r, W1t + (size_t)1024 * D_IN, D_IN, C1);
  transpose_cast_k<<<dim3(C1 / 32, C2 / 32), tb, 0, stream>>>(W2l, W2t, C1, C2);
  transpose_cast_k<<<dim3(C1 / 32, C2 / 32), tb, 0, stream>>>(W2r, W2t + (size_t)256 * C1, C1, C2);
  concat_bias_k<<<8, 256, 0, stream>>>(b1l, b1r, bc1, 1024, 1024);
  concat_bias_k<<<2, 256, 0, stream>>>(b2l, b2r, bc2, 256, 256);

  // ---- CSR by dst (shared by both layers) ----
  count_k<<<1024, 256, 0, stream>>>(ei, counts, E0, E);
  blocksum_k<<<NB, 256, 0, stream>>>(counts, bsum, N);
  scanb_k<<<1, 256, 0, stream>>>(bsum, boff, NB, indptr, N, E);
  scanf_k<<<NB, 256, 0, stream>>>(counts, boff, indptr, N);
  scatter_k<<<1024, 256, 0, stream>>>(ei, indptr, cursor, esrc, E0, E);

  // ---- layer 1 ----
  gemm8_k<2048><<<dim3(Mp / 256, 2048 / 256), 512, 0, stream>>>(A_bf, W1t, bc1, XLR1, D_IN);
  fused_edge1_k<<<Mp, 256, 0, stream>>>(XLR1, indptr, esrc, att1, bias1, X2, N);

  // ---- layer 2 ----
  gemm8_k<512><<<dim3(Mp / 256, 512 / 256), 512, 0, stream>>>(X2, W2t, bc2, XLR2, C1);
  fused_edge2_k<<<(N + 3) / 4, 256, 0, stream>>>(XLR2, indptr, esrc, att2, bias2,
                                                 (float*)d_out, N);
}

// Round 6
// 749.845 us; speedup vs baseline: 1.0318x; 1.0318x over previous
//
#include <hip/hip_runtime.h>
#include <stdint.h>

#define D_IN 1024
#define C1   1024   // H1*HID
#define C2   256    // H2*HID
#define NEG  0.2f

typedef unsigned int u32;
typedef uint16_t u16;
typedef __attribute__((ext_vector_type(8))) short bf16x8;
typedef __attribute__((ext_vector_type(4))) float f32x4;

__device__ __forceinline__ float bf2f(u32 lo16) { return __uint_as_float(lo16 << 16); }
__device__ __forceinline__ u16 f2bf(float f) {
  u32 u = __float_as_uint(f);
  u += 0x7fffu + ((u >> 16) & 1u);   // RNE
  return (u16)(u >> 16);
}

__device__ __forceinline__ void gload16(const u16* g, u16* l) {
  __builtin_amdgcn_global_load_lds(
      (const __attribute__((address_space(1))) unsigned int*)g,
      (__attribute__((address_space(3))) unsigned int*)l,
      16, 0, 0);
}

// ---------------- cast x (f32) -> padded bf16 A [Mp][1024], zero pad rows ----
__global__ void cast_x_k(const float* __restrict__ x, u16* __restrict__ A,
                         int nrows, int Mp) {
  long long idx = (long long)blockIdx.x * blockDim.x + threadIdx.x;
  long long total = (long long)Mp * (D_IN / 8);
  if (idx >= total) return;
  long long base = idx * 8;
  int row = (int)(base >> 10);  // D_IN==1024
  u32 o0 = 0, o1 = 0, o2 = 0, o3 = 0;
  if (row < nrows) {
    const float4* px = (const float4*)(x + base);
    float4 v0 = px[0], v1 = px[1];
    o0 = (u32)f2bf(v0.x) | ((u32)f2bf(v0.y) << 16);
    o1 = (u32)f2bf(v0.z) | ((u32)f2bf(v0.w) << 16);
    o2 = (u32)f2bf(v1.x) | ((u32)f2bf(v1.y) << 16);
    o3 = (u32)f2bf(v1.z) | ((u32)f2bf(v1.w) << 16);
  }
  *(uint4*)(A + base) = make_uint4(o0, o1, o2, o3);
}

// ---------------- transpose+cast W [K][Nc] f32 -> Wt [Nc][K] bf16 ------------
__global__ void transpose_cast_k(const float* __restrict__ W, u16* __restrict__ Wt,
                                 int K, int Nc) {
  __shared__ float sh[32][33];
  int k0 = blockIdx.x * 32, n0 = blockIdx.y * 32;
  int tx = threadIdx.x, ty = threadIdx.y;  // block (32,8)
#pragma unroll
  for (int i = 0; i < 32; i += 8)
    sh[ty + i][tx] = W[(long long)(k0 + ty + i) * Nc + (n0 + tx)];
  __syncthreads();
#pragma unroll
  for (int i = 0; i < 32; i += 8)
    Wt[(long long)(n0 + ty + i) * K + (k0 + tx)] = f2bf(sh[tx][ty + i]);
}

// ---------------- concat two bias vectors -----------------------------------
__global__ void concat_bias_k(const float* __restrict__ a, const float* __restrict__ b,
                              float* __restrict__ o, int na, int nb) {
  int i = blockIdx.x * 256 + threadIdx.x;
  if (i < na) o[i] = a[i];
  else if (i < na + nb) o[i] = b[i - na];
}

// ============ 256x256 BK=64 8-wave phase-interleaved MFMA GEMM ===============
// C[M][TN] = A[M][K] * Bt[TN][K]^T + bias.  512 thr = 8 waves (2M x 4N),
// per-wave 128x64 output (acc[8][4] 16x16 frags).  LDS 128 KiB dbuf.
// T4 deep-counted schedule: stage ALL of tile t+2 late in tile t --
//   ph3: B0,B1(t+2) (Bs[cur] reads ended at ph2's barrier)
//   ph4: A0,A1(t+2) (As[cur] reads ended at ph3's barrier; ph4 has no ds_read)
// (t+2)&1 == t&1, so t+2 stages write buf[cur] -- race-free by the barriers
// above; tile t+1 (buf[cur^1]) is untouched.  ONE wait per tile: vmcnt(8)
// at end-of-tile keeps t+2's 8 loads in flight and requires only t+1's
// loads, all issued >=4 phases (~600+ cy) earlier.  Drain 0 only at tail.
template <int TN>
__global__ __launch_bounds__(512, 2) void gemm8_k(
    const u16* __restrict__ A, const u16* __restrict__ Bt,
    const float* __restrict__ bias, u16* __restrict__ C, int K) {
  __shared__ u16 As[2][2][8192];
  __shared__ u16 Bs[2][2][8192];
  const int nx = gridDim.x, ny = gridDim.y;
  const int nwg = nx * ny;
  int id = blockIdx.y * nx + blockIdx.x;
  int q = nwg >> 3, r = nwg & 7;
  int xcd = id & 7, loc = id >> 3;
  int sid = (xcd < r ? xcd * (q + 1) : r * (q + 1) + (xcd - r) * q) + loc;
  const int m0 = (sid / ny) * 256;   // n varies fastest within an XCD
  const int n0 = (sid % ny) * 256;

  const int tid = threadIdx.x;
  const int lane = tid & 63;
  const int wave = tid >> 6;
  const int wm = wave >> 2;          // 0..1  (A half)
  const int wn = wave & 3;           // 0..3
  const int bh = wn >> 1;            // B half this wave reads
  const int bql = (wn & 1) * 2048;   // B quarter offset within half (u16)

  const int srow = tid >> 2;         // staging row 0..127
  const int kq   = tid & 3;          // physical k-chunk
  const int ksw  = (kq ^ ((srow >> 1) & 3)) * 8;  // swizzled src col (u16)

  const int nt = K / 64;

  const u16* gA[2] = { A + (long long)(m0 + srow) * K + ksw,
                       A + (long long)(m0 + 128 + srow) * K + ksw };
  const u16* gB[2] = { Bt + (long long)(n0 + srow) * K + ksw,
                       Bt + (long long)(n0 + 128 + srow) * K + ksw };

  auto stageA = [&](int kt, int h) {
    int db = kt & 1;
    gload16(gA[h] + kt * 64,      &As[db][h][tid * 8]);
    gload16(gA[h] + kt * 64 + 32, &As[db][h][4096 + tid * 8]);
  };
  auto stageB = [&](int kt, int h) {
    int db = kt & 1;
    gload16(gB[h] + kt * 64,      &Bs[db][h][tid * 8]);
    gload16(gB[h] + kt * 64 + 32, &Bs[db][h][4096 + tid * 8]);
  };

  // fragment read base: frow*32 + physchunk*8 (u16), physchunk = lq ^ s(frow)
  const int rbase = (lane & 15) * 32 + (((lane >> 4) ^ ((lane >> 1) & 3)) << 3);

  f32x4 acc[8][4] = {};
  bf16x8 av[4][2], bv[4][2];

  // ---- prologue: tiles 0 and 1 fully staged; wait for tile 0 only ----
  stageA(0, 0); stageA(0, 1); stageB(0, 0); stageB(0, 1);
  if (nt > 1) {
    stageA(1, 0); stageA(1, 1); stageB(1, 0); stageB(1, 1);
    asm volatile("s_waitcnt vmcnt(8)" ::: "memory");
  } else {
    asm volatile("s_waitcnt vmcnt(0)" ::: "memory");
  }
  __builtin_amdgcn_s_barrier();

  for (int t = 0; t < nt; ++t) {
    const int cur = t & 1;
    const u16* Al = &As[cur][wm][0];
    const u16* Bl = &Bs[cur][bh][0];

    // ---- phase 1: Q1 (m-frags 0..3, n-frags 0..1) ----
#pragma unroll
    for (int i = 0; i < 4; ++i) {
      av[i][0] = *(const bf16x8*)(Al + i * 512 + rbase);
      av[i][1] = *(const bf16x8*)(Al + 4096 + i * 512 + rbase);
    }
#pragma unroll
    for (int j = 0; j < 2; ++j) {
      bv[j][0] = *(const bf16x8*)(Bl + bql + j * 512 + rbase);
      bv[j][1] = *(const bf16x8*)(Bl + 4096 + bql + j * 512 + rbase);
    }
    __builtin_amdgcn_s_barrier();
    __builtin_amdgcn_s_setprio(1);
#pragma unroll
    for (int i = 0; i < 4; ++i)
#pragma unroll
      for (int j = 0; j < 2; ++j) {
        acc[i][j] = __builtin_amdgcn_mfma_f32_16x16x32_bf16(av[i][0], bv[j][0], acc[i][j], 0, 0, 0);
        acc[i][j] = __builtin_amdgcn_mfma_f32_16x16x32_bf16(av[i][1], bv[j][1], acc[i][j], 0, 0, 0);
      }
    __builtin_amdgcn_s_setprio(0);
    __builtin_amdgcn_s_barrier();

    // ---- phase 2: Q2 (m-frags 0..3, n-frags 2..3) ----
#pragma unroll
    for (int j = 2; j < 4; ++j) {
      bv[j][0] = *(const bf16x8*)(Bl + bql + j * 512 + rbase);
      bv[j][1] = *(const bf16x8*)(Bl + 4096 + bql + j * 512 + rbase);
    }
    __builtin_amdgcn_s_barrier();
    __builtin_amdgcn_s_setprio(1);
#pragma unroll
    for (int i = 0; i < 4; ++i)
#pragma unroll
      for (int j = 2; j < 4; ++j) {
        acc[i][j] = __builtin_amdgcn_mfma_f32_16x16x32_bf16(av[i][0], bv[j][0], acc[i][j], 0, 0, 0);
        acc[i][j] = __builtin_amdgcn_mfma_f32_16x16x32_bf16(av[i][1], bv[j][1], acc[i][j], 0, 0, 0);
      }
    __builtin_amdgcn_s_setprio(0);
    __builtin_amdgcn_s_barrier();

    // ---- phase 3: Q3 (m-frags 4..7, n-frags 2..3); stage B0,B1(t+2) ----
#pragma unroll
    for (int i = 0; i < 4; ++i) {
      av[i][0] = *(const bf16x8*)(Al + (4 + i) * 512 + rbase);
      av[i][1] = *(const bf16x8*)(Al + 4096 + (4 + i) * 512 + rbase);
    }
    if (t + 2 < nt) { stageB(t + 2, 0); stageB(t + 2, 1); }
    __builtin_amdgcn_s_barrier();
    __builtin_amdgcn_s_setprio(1);
#pragma unroll
    for (int i = 0; i < 4; ++i)
#pragma unroll
      for (int j = 2; j < 4; ++j) {
        acc[4 + i][j] = __builtin_amdgcn_mfma_f32_16x16x32_bf16(av[i][0], bv[j][0], acc[4 + i][j], 0, 0, 0);
        acc[4 + i][j] = __builtin_amdgcn_mfma_f32_16x16x32_bf16(av[i][1], bv[j][1], acc[4 + i][j], 0, 0, 0);
      }
    __builtin_amdgcn_s_setprio(0);
    __builtin_amdgcn_s_barrier();

    // ---- phase 4: Q4 (m-frags 4..7, n-frags 0..1); stage A0,A1(t+2) ----
    if (t + 2 < nt) { stageA(t + 2, 0); stageA(t + 2, 1); }
    __builtin_amdgcn_s_barrier();
    __builtin_amdgcn_s_setprio(1);
#pragma unroll
    for (int i = 0; i < 4; ++i)
#pragma unroll
      for (int j = 0; j < 2; ++j) {
        acc[4 + i][j] = __builtin_amdgcn_mfma_f32_16x16x32_bf16(av[i][0], bv[j][0], acc[4 + i][j], 0, 0, 0);
        acc[4 + i][j] = __builtin_amdgcn_mfma_f32_16x16x32_bf16(av[i][1], bv[j][1], acc[4 + i][j], 0, 0, 0);
      }
    __builtin_amdgcn_s_setprio(0);
    if (t + 2 < nt) {
      asm volatile("s_waitcnt vmcnt(8)" ::: "memory");   // t+1 landed; t+2 in flight
    } else if (t + 1 < nt) {
      asm volatile("s_waitcnt vmcnt(0)" ::: "memory");   // tail drain
    }
    __builtin_amdgcn_s_barrier();
  }

  // ---- epilogue: D mapping col=lane&15, row=(lane>>4)*4+j ----
#pragma unroll
  for (int mf = 0; mf < 8; ++mf) {
    int r0 = m0 + wm * 128 + mf * 16 + ((lane >> 4) << 2);
#pragma unroll
    for (int nf = 0; nf < 4; ++nf) {
      int c = n0 + wn * 64 + nf * 16 + (lane & 15);
      float b = bias[c];
#pragma unroll
      for (int j = 0; j < 4; ++j)
        C[(long long)(r0 + j) * TN + c] = f2bf(acc[mf][nf][j] + b);
    }
  }
}

// ---------------- CSR build (by dst) ----------------------------------------
__global__ void count_k(const int* __restrict__ ei, int* __restrict__ counts,
                        int E0, int E) {
  for (int e = blockIdx.x * blockDim.x + threadIdx.x; e < E;
       e += gridDim.x * blockDim.x) {
    int dst = (e < E0) ? ei[E0 + e] : e - E0;
    atomicAdd(&counts[dst], 1);
  }
}

// hierarchical scan: blocksum -> scan partials (1 block) -> local scan + off
__global__ void blocksum_k(const int* __restrict__ counts, int* __restrict__ bsum, int n) {
  int i = blockIdx.x * 256 + threadIdx.x;
  int v = (i < n) ? counts[i] : 0;
#pragma unroll
  for (int off = 1; off < 64; off <<= 1) v += __shfl_xor(v, off);
  __shared__ int sh[4];
  if ((threadIdx.x & 63) == 0) sh[threadIdx.x >> 6] = v;
  __syncthreads();
  if (threadIdx.x == 0) bsum[blockIdx.x] = sh[0] + sh[1] + sh[2] + sh[3];
}

__global__ void scanb_k(const int* __restrict__ bsum, int* __restrict__ boff,
                        int nb, int* __restrict__ indptr, int n, int E) {
  __shared__ int sh[256];
  int i = threadIdx.x;
  int v = (i < nb) ? bsum[i] : 0;
  sh[i] = v;
  __syncthreads();
  int sum = v;
  for (int off = 1; off < 256; off <<= 1) {
    int t = (i >= off) ? sh[i - off] : 0;
    __syncthreads();
    sum += t;
    sh[i] = sum;
    __syncthreads();
  }
  if (i < nb) boff[i] = sum - v;  // exclusive
  if (i == 0) indptr[n] = E;
}

__global__ void scanf_k(const int* __restrict__ counts, const int* __restrict__ boff,
                        int* __restrict__ indptr, int n) {
  __shared__ int sh[256];
  int b = blockIdx.x;
  int i = b * 256 + threadIdx.x;
  int v = (i < n) ? counts[i] : 0;
  sh[threadIdx.x] = v;
  __syncthreads();
  int sum = v;
  for (int off = 1; off < 256; off <<= 1) {
    int t = (threadIdx.x >= off) ? sh[threadIdx.x - off] : 0;
    __syncthreads();
    sum += t;
    sh[threadIdx.x] = sum;
    __syncthreads();
  }
  if (i < n) indptr[i] = boff[b] + sum - v;
}

// store SRC id (not edge id) in CSR order
__global__ void scatter_k(const int* __restrict__ ei, const int* __restrict__ indptr,
                          int* __restrict__ cursor, int* __restrict__ esrc,
                          int E0, int E) {
  for (int e = blockIdx.x * blockDim.x + threadIdx.x; e < E;
       e += gridDim.x * blockDim.x) {
    int dst, src;
    if (e < E0) { src = ei[e]; dst = ei[E0 + e]; } else { src = dst = e - E0; }
    int pos = atomicAdd(&cursor[dst], 1);
    esrc[indptr[dst] + pos] = src;
  }
}

// ---------------- fused edge layer 1 (H=4): alpha+softmax+agg, online --------
// 2-deep gather pipeline: xl[p+2] issued before computing edge p.
__global__ __launch_bounds__(256) void fused_edge1_k(
    const u16* __restrict__ XLR, const int* __restrict__ indptr,
    const int* __restrict__ esrc, const float* __restrict__ att,
    const float* __restrict__ bias, u16* __restrict__ X2, int N) {
  int d = blockIdx.x;
  int tid = threadIdx.x;
  int c0 = tid * 4;  // channel in [0,1024); head = tid>>6
  if (d >= N) {
    *(ushort4*)(X2 + (long long)d * C1 + c0) = make_ushort4(0, 0, 0, 0);
    return;
  }
  ushort4 xr4 = *(const ushort4*)(XLR + (long long)d * 2048 + 1024 + c0);
  float xr0 = bf2f(xr4.x), xr1 = bf2f(xr4.y), xr2 = bf2f(xr4.z), xr3 = bf2f(xr4.w);
  float4 at = *(const float4*)(att + c0);

  float m = -INFINITY, l = 0.f;
  float a0 = 0.f, a1 = 0.f, a2 = 0.f, a3 = 0.f;
  int p = indptr[d], pend = indptr[d + 1];
  ushort4 xlA = *(const ushort4*)(XLR + (long long)esrc[p] * 2048 + c0);
  ushort4 xlB = make_ushort4(0, 0, 0, 0);
  if (p + 1 < pend)
    xlB = *(const ushort4*)(XLR + (long long)esrc[p + 1] * 2048 + c0);
  for (; p < pend; ++p) {
    ushort4 cur = xlA;
    xlA = xlB;
    if (p + 2 < pend)
      xlB = *(const ushort4*)(XLR + (long long)esrc[p + 2] * 2048 + c0);
    float x0 = bf2f(cur.x), x1 = bf2f(cur.y), x2 = bf2f(cur.z), x3 = bf2f(cur.w);
    float m0 = x0 + xr0, m1 = x1 + xr1, m2 = x2 + xr2, m3 = x3 + xr3;
    float e0 = m0 > 0.f ? m0 : NEG * m0;
    float e1 = m1 > 0.f ? m1 : NEG * m1;
    float e2 = m2 > 0.f ? m2 : NEG * m2;
    float e3 = m3 > 0.f ? m3 : NEG * m3;
    float s = at.x * e0 + at.y * e1 + at.z * e2 + at.w * e3;
#pragma unroll
    for (int off = 1; off < 64; off <<= 1) s += __shfl_xor(s, off);
    float mnew = fmaxf(m, s);
    float scale = __expf(m - mnew);  // first iter: exp(-inf)=0
    float w = __expf(s - mnew);
    l = l * scale + w;
    a0 = a0 * scale + w * x0;
    a1 = a1 * scale + w * x1;
    a2 = a2 * scale + w * x2;
    a3 = a3 * scale + w * x3;
    m = mnew;
  }
  float inv = 1.f / (l + 1e-16f);
  float4 b = *(const float4*)(bias + c0);
  ushort4 o;
  o.x = f2bf(fmaxf(a0 * inv + b.x, 0.f));
  o.y = f2bf(fmaxf(a1 * inv + b.y, 0.f));
  o.z = f2bf(fmaxf(a2 * inv + b.z, 0.f));
  o.w = f2bf(fmaxf(a3 * inv + b.w, 0.f));
  *(ushort4*)(X2 + (long long)d * C1 + c0) = o;
}

// ---------------- fused edge layer 2 (H=1): one wave per dst, f32 out --------
__global__ __launch_bounds__(256) void fused_edge2_k(
    const u16* __restrict__ XLR, const int* __restrict__ indptr,
    const int* __restrict__ esrc, const float* __restrict__ att,
    const float* __restrict__ bias, float* __restrict__ out, int N) {
  int d = blockIdx.x * 4 + (threadIdx.x >> 6);
  if (d >= N) return;
  int lane = threadIdx.x & 63;
  int c0 = lane * 4;
  ushort4 xr4 = *(const ushort4*)(XLR + (long long)d * 512 + 256 + c0);
  float xr0 = bf2f(xr4.x), xr1 = bf2f(xr4.y), xr2 = bf2f(xr4.z), xr3 = bf2f(xr4.w);
  float4 at = *(const float4*)(att + c0);

  float m = -INFINITY, l = 0.f;
  float a0 = 0.f, a1 = 0.f, a2 = 0.f, a3 = 0.f;
  int p = indptr[d], pend = indptr[d + 1];
  ushort4 xlA = *(const ushort4*)(XLR + (long long)esrc[p] * 512 + c0);
  ushort4 xlB = make_ushort4(0, 0, 0, 0);
  if (p + 1 < pend)
    xlB = *(const ushort4*)(XLR + (long long)esrc[p + 1] * 512 + c0);
  for (; p < pend; ++p) {
    ushort4 cur = xlA;
    xlA = xlB;
    if (p + 2 < pend)
      xlB = *(const ushort4*)(XLR + (long long)esrc[p + 2] * 512 + c0);
    float x0 = bf2f(cur.x), x1 = bf2f(cur.y), x2 = bf2f(cur.z), x3 = bf2f(cur.w);
    float m0 = x0 + xr0, m1 = x1 + xr1, m2 = x2 + xr2, m3 = x3 + xr3;
    float e0 = m0 > 0.f ? m0 : NEG * m0;
    float e1 = m1 > 0.f ? m1 : NEG * m1;
    float e2 = m2 > 0.f ? m2 : NEG * m2;
    float e3 = m3 > 0.f ? m3 : NEG * m3;
    float s = at.x * e0 + at.y * e1 + at.z * e2 + at.w * e3;
#pragma unroll
    for (int off = 1; off < 64; off <<= 1) s += __shfl_xor(s, off);
    float mnew = fmaxf(m, s);
    float scale = __expf(m - mnew);
    float w = __expf(s - mnew);
    l = l * scale + w;
    a0 = a0 * scale + w * x0;
    a1 = a1 * scale + w * x1;
    a2 = a2 * scale + w * x2;
    a3 = a3 * scale + w * x3;
    m = mnew;
  }
  float inv = 1.f / (l + 1e-16f);
  float4 b = *(const float4*)(bias + c0);
  float4 o;
  o.x = fmaxf(a0 * inv + b.x, 0.f);
  o.y = fmaxf(a1 * inv + b.y, 0.f);
  o.z = fmaxf(a2 * inv + b.z, 0.f);
  o.w = fmaxf(a3 * inv + b.w, 0.f);
  *(float4*)(out + (long long)d * C2 + c0) = o;
}

// =============================================================================
extern "C" void kernel_launch(void* const* d_in, const int* in_sizes, int n_in,
                              void* d_out, int out_size, void* d_ws, size_t ws_size,
                              hipStream_t stream) {
  const float* x     = (const float*)d_in[0];
  const int*   ei    = (const int*)d_in[1];
  const float* W1l   = (const float*)d_in[2];
  const float* b1l   = (const float*)d_in[3];
  const float* W1r   = (const float*)d_in[4];
  const float* b1r   = (const float*)d_in[5];
  const float* att1  = (const float*)d_in[6];
  const float* bias1 = (const float*)d_in[7];
  const float* W2l   = (const float*)d_in[8];
  const float* b2l   = (const float*)d_in[9];
  const float* W2r   = (const float*)d_in[10];
  const float* b2r   = (const float*)d_in[11];
  const float* att2  = (const float*)d_in[12];
  const float* bias2 = (const float*)d_in[13];

  const int N  = in_sizes[0] / D_IN;  // 50000
  const int E0 = in_sizes[1] / 2;     // 400000
  const int E  = E0 + N;              // with self-loops
  const int Mp = (N + 255) & ~255;    // 50176 (multiple of 256)
  const int NB = (N + 255) / 256;     // scan blocks (196)

  char* p = (char*)d_ws;
  auto alloc = [&](size_t bytes) -> char* {
    char* r = p;
    p += (bytes + 255) & ~(size_t)255;
    return r;
  };
  u16* A_bf  = (u16*)alloc((size_t)Mp * D_IN * 2);   // x bf16; later X2 (layer-2 A)
  u16* XLR1  = (u16*)alloc((size_t)Mp * 2048 * 2);   // [xl|xr] layer 1; later XLR2
  u16* W1t   = (u16*)alloc((size_t)2048 * D_IN * 2);
  u16* W2t   = (u16*)alloc((size_t)512 * C1 * 2);
  float* bc1 = (float*)alloc(2048 * 4);
  float* bc2 = (float*)alloc(512 * 4);
  int* counts = (int*)alloc((size_t)N * 4);
  int* cursor = (int*)alloc((size_t)N * 4);
  int* indptr = (int*)alloc((size_t)(N + 1) * 4);
  int* esrc   = (int*)alloc((size_t)E * 4);
  int* bsum   = (int*)alloc((size_t)NB * 4);
  int* boff   = (int*)alloc((size_t)NB * 4);
  u16* X2   = A_bf;   // alias: A_bf dead after GEMM1
  u16* XLR2 = XLR1;   // alias: XLR1 dead after fused_edge1

  size_t need = (size_t)(p - (char*)d_ws);
  if (ws_size < need) {
    hipMemsetAsync(d_out, 0xFF, 4, stream);  // NaN sentinel
    return;
  }

  hipMemsetAsync(counts, 0, (size_t)N * 4, stream);
  hipMemsetAsync(cursor, 0, (size_t)N * 4, stream);

  // ---- casts / transposes / bias concat ----
  {
    long long tot = (long long)Mp * (D_IN / 8);
    cast_x_k<<<(int)((tot + 255) / 256), 256, 0, stream>>>(x, A_bf, N, Mp);
  }
  dim3 tb(32, 8);
  transpose_cast_k<<<dim3(D_IN / 32, C1 / 32), tb, 0, stream>>>(W1l, W1t, D_IN, C1);
  transpose_cast_k<<<dim3(D_IN / 32, C1 / 32), tb, 0, stream>>>(W1r, W1t + (size_t)1024 * D_IN, D_IN, C1);
  transpose_cast_k<<<dim3(C1 / 32, C2 / 32), tb, 0, stream>>>(W2l, W2t, C1, C2);
  transpose_cast_k<<<dim3(C1 / 32, C2 / 32), tb, 0, stream>>>(W2r, W2t + (size_t)256 * C1, C1, C2);
  concat_bias_k<<<8, 256, 0, stream>>>(b1l, b1r, bc1, 1024, 1024);
  concat_bias_k<<<2, 256, 0, stream>>>(b2l, b2r, bc2, 256, 256);

  // ---- CSR by dst (shared by both layers) ----
  count_k<<<1024, 256, 0, stream>>>(ei, counts, E0, E);
  blocksum_k<<<NB, 256, 0, stream>>>(counts, bsum, N);
  scanb_k<<<1, 256, 0, stream>>>(bsum, boff, NB, indptr, N, E);
  scanf_k<<<NB, 256, 0, stream>>>(counts, boff, indptr, N);
  scatter_k<<<1024, 256, 0, stream>>>(ei, indptr, cursor, esrc, E0, E);

  // ---- layer 1 ----
  gemm8_k<2048><<<dim3(Mp / 256, 2048 / 256), 512, 0, stream>>>(A_bf, W1t, bc1, XLR1, D_IN);
  fused_edge1_k<<<Mp, 256, 0, stream>>>(XLR1, indptr, esrc, att1, bias1, X2, N);

  // ---- layer 2 ----
  gemm8_k<512><<<dim3(Mp / 256, 512 / 256), 512, 0, stream>>>(X2, W2t, bc2, XLR2, C1);
  fused_edge2_k<<<(N + 3) / 4, 256, 0, stream>>>(XLR2, indptr, esrc, att2, bias2,
                                                 (float*)d_out, N);
}